// Round 4
// baseline (124.077 us; speedup 1.0000x reference)
//
#include <hip/hip_runtime.h>
#include <stdint.h>

#define K_   128
#define GD_  128
#define PSTR 20   // floats per (b,k) param record

// Constant-address-space (AS4) pointer types: loads from these with
// wave-uniform addresses select SMEM (s_load_*) -> SGPRs, shared by the
// whole wave. Zero DS-pipe and zero vector-L1 cost for the param stream.
typedef float vf4 __attribute__((ext_vector_type(4)));
typedef const __attribute__((address_space(4))) float  cfloat;
typedef const __attribute__((address_space(4))) vf4    cvf4;

static __device__ __forceinline__ float fast_exp2(float x) {
#if __has_builtin(__builtin_amdgcn_exp2f)
    return __builtin_amdgcn_exp2f(x);
#else
    return exp2f(x);
#endif
}

// ---------------- param kernel: one thread per (b,k) ----------------
//   G  = A_next * (R_next * R^T)            (3x3, grid-space transform)
//   v  = A_next * (c_next - R_rel*c) + t_next
//   q  = 2*s*log2e * c,  r = log2(c^2) - s*log2e*|c|^2,  s2n = -s*log2e
// Per point:  log2(w) = q.p + s2n*|p|^2 + r,  gridcoord = (Σw(G p + v))/Σw
// (world2grid + [-1,1] normalization + grid_sample denorm cancel exactly.)
__global__ void surf_param_kernel(
    const float* __restrict__ constants,
    const float* __restrict__ scales,
    const float* __restrict__ rotations,
    const float* __restrict__ centers,
    const float* __restrict__ w2g,
    float* __restrict__ params,
    float* __restrict__ out,
    int B)
{
    int idx = blockIdx.x * blockDim.x + threadIdx.x;
    if (idx == 0) out[0] = 0.0f;           // fused memset (runs before main kernel)
    if (idx >= B * K_) return;
    int b = idx / K_, k = idx - b * K_;
    int bn = (b + 1 == B) ? 0 : (b + 1);
    const float L2E = 1.4426950408889634f;

    const float* R  = rotations + (size_t)(b  * K_ + k) * 9;
    const float* Rt = rotations + (size_t)(bn * K_ + k) * 9;
    float m[9];
#pragma unroll
    for (int i = 0; i < 3; ++i)
#pragma unroll
        for (int l = 0; l < 3; ++l)
            m[i * 3 + l] = Rt[i * 3 + 0] * R[l * 3 + 0]
                         + Rt[i * 3 + 1] * R[l * 3 + 1]
                         + Rt[i * 3 + 2] * R[l * 3 + 2];

    const float* Aw = w2g + (size_t)bn * 16;   // rows [a0 a1 a2 t]
    float G[9], A[9] = {Aw[0], Aw[1], Aw[2], Aw[4], Aw[5], Aw[6], Aw[8], Aw[9], Aw[10]};
    float T[3] = {Aw[3], Aw[7], Aw[11]};
#pragma unroll
    for (int i = 0; i < 3; ++i)
#pragma unroll
        for (int l = 0; l < 3; ++l)
            G[i * 3 + l] = A[i * 3 + 0] * m[0 * 3 + l]
                         + A[i * 3 + 1] * m[1 * 3 + l]
                         + A[i * 3 + 2] * m[2 * 3 + l];

    const float* c  = centers + (size_t)(b  * K_ + k) * 3;
    const float* ct = centers + (size_t)(bn * K_ + k) * 3;
    float c0 = c[0], c1 = c[1], c2 = c[2];
    float vw0 = ct[0] - (m[0] * c0 + m[1] * c1 + m[2] * c2);
    float vw1 = ct[1] - (m[3] * c0 + m[4] * c1 + m[5] * c2);
    float vw2 = ct[2] - (m[6] * c0 + m[7] * c1 + m[8] * c2);
    float v0 = A[0] * vw0 + A[1] * vw1 + A[2] * vw2 + T[0];
    float v1 = A[3] * vw0 + A[4] * vw1 + A[5] * vw2 + T[1];
    float v2 = A[6] * vw0 + A[7] * vw1 + A[8] * vw2 + T[2];

    float sig = scales[b * K_ + k];
    float s   = 1.0f / (2.0f * sig * sig);
    float con = constants[b * K_ + k];
    float s2n = -s * L2E;
    float r   = log2f(con * con) + s2n * (c0 * c0 + c1 * c1 + c2 * c2);

    float* o = params + (size_t)idx * PSTR;
    o[0] = G[0]; o[1] = G[1]; o[2] = G[2]; o[3] = G[3];
    o[4] = G[4]; o[5] = G[5]; o[6] = G[6]; o[7] = G[7];
    o[8] = G[8]; o[9] = v0;  o[10] = v1;  o[11] = v2;
    o[12] = -2.0f * s2n * c0;
    o[13] = -2.0f * s2n * c1;
    o[14] = -2.0f * s2n * c2;
    o[15] = r;
    o[16] = s2n;
    o[17] = 0.f; o[18] = 0.f; o[19] = 0.f;
}

// ---------------- main kernel: 2 points per thread, params via s_load ----------------
#define PPT 2
__global__ __launch_bounds__(256) void surf_loss_kernel(
    const float* __restrict__ sp,      // (B,N,6)
    const float* __restrict__ grid,    // (B,GD,GD,GD)
    const float* __restrict__ params,  // (B,K,PSTR) precomputed
    float* __restrict__ out,
    int N, int B, int bpb)
{
    const int tid = threadIdx.x;
    const int blk = blockIdx.x;
    const int b   = blk / bpb;
    const int n0  = (blk - b * bpb) * (256 * PPT) + tid;
    const int bn  = (b + 1 == B) ? 0 : (b + 1);

    // constant-AS view of this batch's param table (wave-uniform address)
    cfloat* Pc = (cfloat*)(uintptr_t)(params + (size_t)b * K_ * PSTR);

    float px[PPT], py[PPT], pz[PPT], pq[PPT];
    float ax[PPT], ay[PPT], az[PPT], aw[PPT];
    bool  valid[PPT];
    const float* spb = sp + (size_t)b * N * 6;
#pragma unroll
    for (int j = 0; j < PPT; ++j) {
        int n = n0 + 256 * j;
        valid[j] = (n < N);
        const float* q = spb + (size_t)(valid[j] ? n : 0) * 6;
        px[j] = q[0]; py[j] = q[1]; pz[j] = q[2];
        pq[j] = px[j] * px[j] + py[j] * py[j] + pz[j] * pz[j];
        ax[j] = 0.f; ay[j] = 0.f; az[j] = 0.f; aw[j] = 0.f;
    }

#pragma unroll 2
    for (int k = 0; k < K_; ++k) {
        cfloat* o = Pc + k * PSTR;
        vf4 f0 = ((cvf4*)o)[0];   // G00 G01 G02 G10
        vf4 f1 = ((cvf4*)o)[1];   // G11 G12 G20 G21
        vf4 f2 = ((cvf4*)o)[2];   // G22 v0  v1  v2
        vf4 f3 = ((cvf4*)o)[3];   // q0  q1  q2  r
        float s2 = o[16];
#pragma unroll
        for (int j = 0; j < PPT; ++j) {
            float e = f3.w + f3.x * px[j] + f3.y * py[j] + f3.z * pz[j] + s2 * pq[j];
            float w = fast_exp2(e);
            float tx = f2.y + f0.x * px[j] + f0.y * py[j] + f0.z * pz[j];
            float ty = f2.z + f0.w * px[j] + f1.x * py[j] + f1.y * pz[j];
            float tz = f2.w + f1.z * px[j] + f1.w * py[j] + f2.x * pz[j];
            ax[j] += w * tx;
            ay[j] += w * ty;
            az[j] += w * tz;
            aw[j] += w;
        }
    }

    const float* gb = grid + (size_t)bn * GD_ * GD_ * GD_;
    float accum = 0.0f;
#pragma unroll
    for (int j = 0; j < PPT; ++j) {
        if (!valid[j]) continue;
        float inv = 1.0f / aw[j];
        float x = fminf(fmaxf(ax[j] * inv, 0.0f), (float)(GD_ - 1));
        float y = fminf(fmaxf(ay[j] * inv, 0.0f), (float)(GD_ - 1));
        float z = fminf(fmaxf(az[j] * inv, 0.0f), (float)(GD_ - 1));
        float x0f = floorf(x), y0f = floorf(y), z0f = floorf(z);
        float fx = x - x0f, fy = y - y0f, fz = z - z0f;
        int x0 = (int)x0f, y0 = (int)y0f, z0 = (int)z0f;
        int x1 = x0 + 1 > GD_ - 1 ? GD_ - 1 : x0 + 1;
        int y1 = y0 + 1 > GD_ - 1 ? GD_ - 1 : y0 + 1;
        int z1 = z0 + 1 > GD_ - 1 ? GD_ - 1 : z0 + 1;
        int zy00 = (z0 * GD_ + y0) * GD_;
        int zy01 = (z0 * GD_ + y1) * GD_;
        int zy10 = (z1 * GD_ + y0) * GD_;
        int zy11 = (z1 * GD_ + y1) * GD_;
        float c000 = gb[zy00 + x0], c001 = gb[zy00 + x1];
        float c010 = gb[zy01 + x0], c011 = gb[zy01 + x1];
        float c100 = gb[zy10 + x0], c101 = gb[zy10 + x1];
        float c110 = gb[zy11 + x0], c111 = gb[zy11 + x1];
        float ofx = 1.0f - fx, ofy = 1.0f - fy, ofz = 1.0f - fz;
        float c00 = c000 * ofx + c001 * fx;
        float c01 = c010 * ofx + c011 * fx;
        float c10 = c100 * ofx + c101 * fx;
        float c11 = c110 * ofx + c111 * fx;
        float c0 = c00 * ofy + c01 * fy;
        float c1 = c10 * ofy + c11 * fy;
        float sdf = c0 * ofz + c1 * fz;
        accum += sdf * sdf;
    }

    // ---- block reduction: per-wave shuffle, then LDS across 4 waves ----
    __shared__ float red[4];
#pragma unroll
    for (int off = 32; off > 0; off >>= 1)
        accum += __shfl_down(accum, off, 64);
    int wave = tid >> 6;
    if ((tid & 63) == 0) red[wave] = accum;
    __syncthreads();
    if (tid == 0)
        atomicAdd(out, (red[0] + red[1] + red[2] + red[3]) * (1.0f / (float)N));
}

extern "C" void kernel_launch(void* const* d_in, const int* in_sizes, int n_in,
                              void* d_out, int out_size, void* d_ws, size_t ws_size,
                              hipStream_t stream) {
    const float* constants = (const float*)d_in[0];
    const float* scales    = (const float*)d_in[1];
    const float* rotations = (const float*)d_in[2];
    const float* centers   = (const float*)d_in[3];
    const float* sp        = (const float*)d_in[4];
    const float* grid      = (const float*)d_in[5];
    const float* w2g       = (const float*)d_in[6];
    float* out = (float*)d_out;
    float* params = (float*)d_ws;            // B*K_*PSTR floats = 40 KB

    const int B = in_sizes[6] / 16;          // 4
    const int N = in_sizes[4] / (6 * B);     // 50000

    int np = B * K_;
    hipLaunchKernelGGL(surf_param_kernel, dim3((np + 255) / 256), dim3(256), 0, stream,
                       constants, scales, rotations, centers, w2g, params, out, B);

    const int ppb = 256 * PPT;               // points per block
    const int bpb = (N + ppb - 1) / ppb;     // blocks per batch
    hipLaunchKernelGGL(surf_loss_kernel, dim3(B * bpb), dim3(256), 0, stream,
                       sp, grid, params, out, N, B, bpb);
}

// Round 5
// 113.107 us; speedup vs baseline: 1.0970x; 1.0970x over previous
//
#include <hip/hip_runtime.h>
#include <stdint.h>

#define K_   128
#define GD_  128
#define PSTR 20   // floats per (b,k) param record
#define KPW  32   // k's per wave (K_ / 4 waves)

static __device__ __forceinline__ float fast_exp2(float x) {
#if __has_builtin(__builtin_amdgcn_exp2f)
    return __builtin_amdgcn_exp2f(x);
#else
    return exp2f(x);
#endif
}

// ---------------- param kernel: one thread per (b,k) ----------------
//   G  = A_next * (R_next * R^T)            (3x3, grid-space transform)
//   v  = A_next * (c_next - R_rel*c) + t_next
//   q  = 2*s*log2e * c,  r = log2(c^2) - s*log2e*|c|^2,  s2n = -s*log2e
// Per point:  log2(w) = q.p + s2n*|p|^2 + r,  gridcoord = (Σw(G p + v))/Σw
// (world2grid + [-1,1] normalization + grid_sample denorm cancel exactly.)
__global__ void surf_param_kernel(
    const float* __restrict__ constants,
    const float* __restrict__ scales,
    const float* __restrict__ rotations,
    const float* __restrict__ centers,
    const float* __restrict__ w2g,
    float* __restrict__ params,
    float* __restrict__ out,
    int B)
{
    int idx = blockIdx.x * blockDim.x + threadIdx.x;
    if (idx == 0) out[0] = 0.0f;           // fused memset (runs before main kernel)
    if (idx >= B * K_) return;
    int b = idx / K_, k = idx - b * K_;
    int bn = (b + 1 == B) ? 0 : (b + 1);
    const float L2E = 1.4426950408889634f;

    const float* R  = rotations + (size_t)(b  * K_ + k) * 9;
    const float* Rt = rotations + (size_t)(bn * K_ + k) * 9;
    float m[9];
#pragma unroll
    for (int i = 0; i < 3; ++i)
#pragma unroll
        for (int l = 0; l < 3; ++l)
            m[i * 3 + l] = Rt[i * 3 + 0] * R[l * 3 + 0]
                         + Rt[i * 3 + 1] * R[l * 3 + 1]
                         + Rt[i * 3 + 2] * R[l * 3 + 2];

    const float* Aw = w2g + (size_t)bn * 16;   // rows [a0 a1 a2 t]
    float G[9], A[9] = {Aw[0], Aw[1], Aw[2], Aw[4], Aw[5], Aw[6], Aw[8], Aw[9], Aw[10]};
    float T[3] = {Aw[3], Aw[7], Aw[11]};
#pragma unroll
    for (int i = 0; i < 3; ++i)
#pragma unroll
        for (int l = 0; l < 3; ++l)
            G[i * 3 + l] = A[i * 3 + 0] * m[0 * 3 + l]
                         + A[i * 3 + 1] * m[1 * 3 + l]
                         + A[i * 3 + 2] * m[2 * 3 + l];

    const float* c  = centers + (size_t)(b  * K_ + k) * 3;
    const float* ct = centers + (size_t)(bn * K_ + k) * 3;
    float c0 = c[0], c1 = c[1], c2 = c[2];
    float vw0 = ct[0] - (m[0] * c0 + m[1] * c1 + m[2] * c2);
    float vw1 = ct[1] - (m[3] * c0 + m[4] * c1 + m[5] * c2);
    float vw2 = ct[2] - (m[6] * c0 + m[7] * c1 + m[8] * c2);
    float v0 = A[0] * vw0 + A[1] * vw1 + A[2] * vw2 + T[0];
    float v1 = A[3] * vw0 + A[4] * vw1 + A[5] * vw2 + T[1];
    float v2 = A[6] * vw0 + A[7] * vw1 + A[8] * vw2 + T[2];

    float sig = scales[b * K_ + k];
    float s   = 1.0f / (2.0f * sig * sig);
    float con = constants[b * K_ + k];
    float s2n = -s * L2E;
    float r   = log2f(con * con) + s2n * (c0 * c0 + c1 * c1 + c2 * c2);

    float* o = params + (size_t)idx * PSTR;
    o[0] = G[0]; o[1] = G[1]; o[2] = G[2]; o[3] = G[3];
    o[4] = G[4]; o[5] = G[5]; o[6] = G[6]; o[7] = G[7];
    o[8] = G[8]; o[9] = v0;  o[10] = v1;  o[11] = v2;
    o[12] = -2.0f * s2n * c0;
    o[13] = -2.0f * s2n * c1;
    o[14] = -2.0f * s2n * c2;
    o[15] = r;
    o[16] = s2n;
    o[17] = 0.f; o[18] = 0.f; o[19] = 0.f;
}

// ---------------- main kernel: K split across the block's 4 waves ----------------
// Block = 256 threads = 4 waves, handles 256 points of one batch.
// Wave w computes partial (ax,ay,az,aw) over k in [32w, 32w+32) for all 256
// points (4 per thread); partials combined through LDS; epilogue split by wave.
// This holds occupancy at 3136 waves (3.06/SIMD) while cutting the per-wave
// LDS-broadcast param stream 4x vs round 3 (the measured DS-throughput bound).
__global__ __launch_bounds__(256) void surf_loss_kernel(
    const float* __restrict__ sp,      // (B,N,6)
    const float* __restrict__ grid,    // (B,GD,GD,GD)
    const float* __restrict__ params,  // (B,K,PSTR) precomputed
    float* __restrict__ out,
    int N, int B, int bpb)
{
    __shared__ float  lds_par[K_ * PSTR];      // 10 KB
    __shared__ float4 lds_part[4 * 4 * 64];    // 16 KB: [wave][j][lane]
    __shared__ float  red[4];

    const int tid  = threadIdx.x;
    const int lane = tid & 63;
    const int wave = tid >> 6;
    const int blk  = blockIdx.x;
    const int b    = blk / bpb;
    const int base = (blk - b * bpb) * 256;
    const int bn   = (b + 1 == B) ? 0 : (b + 1);

    // stage batch's param table into LDS, coalesced float4
    {
        const float4* Pv = (const float4*)(params + (size_t)b * K_ * PSTR);
        float4* Lv = (float4*)lds_par;
        for (int t = tid; t < K_ * PSTR / 4; t += 256)
            Lv[t] = Pv[t];
    }

    // load this thread's 4 points (same 4 points in every wave, same lane)
    float px[4], py[4], pz[4], pq[4];
    float ax[4], ay[4], az[4], aw[4];
    const float* spb = sp + (size_t)b * N * 6;
#pragma unroll
    for (int j = 0; j < 4; ++j) {
        int n = base + j * 64 + lane;
        int nn = (n < N) ? n : 0;
        const float* q = spb + (size_t)nn * 6;
        px[j] = q[0]; py[j] = q[1]; pz[j] = q[2];
        pq[j] = px[j] * px[j] + py[j] * py[j] + pz[j] * pz[j];
        ax[j] = 0.f; ay[j] = 0.f; az[j] = 0.f; aw[j] = 0.f;
    }

    __syncthreads();

    // K loop: this wave's 32 k's only
    const int k0 = wave * KPW;
#pragma unroll 2
    for (int kk = 0; kk < KPW; ++kk) {
        const float4* f = (const float4*)(lds_par + (k0 + kk) * PSTR);
        const float4 f0 = f[0];   // G00 G01 G02 G10
        const float4 f1 = f[1];   // G11 G12 G20 G21
        const float4 f2 = f[2];   // G22 v0  v1  v2
        const float4 f3 = f[3];   // q0  q1  q2  r
        const float  s2 = lds_par[(k0 + kk) * PSTR + 16];
#pragma unroll
        for (int j = 0; j < 4; ++j) {
            float e = f3.w + f3.x * px[j] + f3.y * py[j] + f3.z * pz[j] + s2 * pq[j];
            float w = fast_exp2(e);
            float tx = f2.y + f0.x * px[j] + f0.y * py[j] + f0.z * pz[j];
            float ty = f2.z + f0.w * px[j] + f1.x * py[j] + f1.y * pz[j];
            float tz = f2.w + f1.z * px[j] + f1.w * py[j] + f2.x * pz[j];
            ax[j] += w * tx;
            ay[j] += w * ty;
            az[j] += w * tz;
            aw[j] += w;
        }
    }

    // write partials: [wave][j][lane]
#pragma unroll
    for (int j = 0; j < 4; ++j)
        lds_part[((wave * 4 + j) << 6) + lane] = make_float4(ax[j], ay[j], az[j], aw[j]);
    __syncthreads();

    // epilogue: wave w takes point group j == wave
    float accum = 0.0f;
    {
        int n = base + wave * 64 + lane;
        if (n < N) {
            float sx = 0.f, sy = 0.f, sz = 0.f, sw = 0.f;
#pragma unroll
            for (int w = 0; w < 4; ++w) {
                float4 t = lds_part[((w * 4 + wave) << 6) + lane];
                sx += t.x; sy += t.y; sz += t.z; sw += t.w;
            }
            float inv = 1.0f / sw;
            float x = fminf(fmaxf(sx * inv, 0.0f), (float)(GD_ - 1));
            float y = fminf(fmaxf(sy * inv, 0.0f), (float)(GD_ - 1));
            float z = fminf(fmaxf(sz * inv, 0.0f), (float)(GD_ - 1));
            float x0f = floorf(x), y0f = floorf(y), z0f = floorf(z);
            float fx = x - x0f, fy = y - y0f, fz = z - z0f;
            int x0 = (int)x0f, y0 = (int)y0f, z0 = (int)z0f;
            int x1 = x0 + 1 > GD_ - 1 ? GD_ - 1 : x0 + 1;
            int y1 = y0 + 1 > GD_ - 1 ? GD_ - 1 : y0 + 1;
            int z1 = z0 + 1 > GD_ - 1 ? GD_ - 1 : z0 + 1;
            const float* gb = grid + (size_t)bn * GD_ * GD_ * GD_;
            int zy00 = (z0 * GD_ + y0) * GD_;
            int zy01 = (z0 * GD_ + y1) * GD_;
            int zy10 = (z1 * GD_ + y0) * GD_;
            int zy11 = (z1 * GD_ + y1) * GD_;
            float c000 = gb[zy00 + x0], c001 = gb[zy00 + x1];
            float c010 = gb[zy01 + x0], c011 = gb[zy01 + x1];
            float c100 = gb[zy10 + x0], c101 = gb[zy10 + x1];
            float c110 = gb[zy11 + x0], c111 = gb[zy11 + x1];
            float ofx = 1.0f - fx, ofy = 1.0f - fy, ofz = 1.0f - fz;
            float c00 = c000 * ofx + c001 * fx;
            float c01 = c010 * ofx + c011 * fx;
            float c10 = c100 * ofx + c101 * fx;
            float c11 = c110 * ofx + c111 * fx;
            float c0 = c00 * ofy + c01 * fy;
            float c1 = c10 * ofy + c11 * fy;
            float sdf = c0 * ofz + c1 * fz;
            accum = sdf * sdf;
        }
    }

    // per-wave shuffle reduce, then one atomic per block
#pragma unroll
    for (int off = 32; off > 0; off >>= 1)
        accum += __shfl_down(accum, off, 64);
    if (lane == 0) red[wave] = accum;
    __syncthreads();
    if (tid == 0)
        atomicAdd(out, (red[0] + red[1] + red[2] + red[3]) * (1.0f / (float)N));
}

extern "C" void kernel_launch(void* const* d_in, const int* in_sizes, int n_in,
                              void* d_out, int out_size, void* d_ws, size_t ws_size,
                              hipStream_t stream) {
    const float* constants = (const float*)d_in[0];
    const float* scales    = (const float*)d_in[1];
    const float* rotations = (const float*)d_in[2];
    const float* centers   = (const float*)d_in[3];
    const float* sp        = (const float*)d_in[4];
    const float* grid      = (const float*)d_in[5];
    const float* w2g       = (const float*)d_in[6];
    float* out = (float*)d_out;
    float* params = (float*)d_ws;            // B*K_*PSTR floats = 40 KB

    const int B = in_sizes[6] / 16;          // 4
    const int N = in_sizes[4] / (6 * B);     // 50000

    int np = B * K_;
    hipLaunchKernelGGL(surf_param_kernel, dim3((np + 255) / 256), dim3(256), 0, stream,
                       constants, scales, rotations, centers, w2g, params, out, B);

    const int bpb = (N + 255) / 256;         // blocks per batch (256 points/block)
    hipLaunchKernelGGL(surf_loss_kernel, dim3(B * bpb), dim3(256), 0, stream,
                       sp, grid, params, out, N, B, bpb);
}